// Round 14
// baseline (207.728 us; speedup 1.0000x reference)
//
#include <hip/hip_runtime.h>
#include <stdint.h>

typedef unsigned short u16t;
typedef __attribute__((ext_vector_type(8))) short bf16x8;
typedef __attribute__((ext_vector_type(4))) float f32x4;

__device__ __forceinline__ float2 up2(uint32_t u) {
    return make_float2(__uint_as_float(u << 16), __uint_as_float(u & 0xFFFF0000u));
}
__device__ __forceinline__ uint32_t pk_bf16(float a, float b) {
    uint32_t r;
    asm("v_cvt_pk_bf16_f32 %0, %1, %2" : "=v"(r) : "v"(a), "v"(b));
    return r;   // lo16 = bf16(a) RNE, hi16 = bf16(b)
}

// ---------------------------------------------------------------------------
// Pre-kernel (35 blocks):
//  blocks 0-31 : W1d (1024x64 fp32) -> Wt bf16 [g][k][o][j]   (131072 B)
//  blocks 32-34: W2d (16x384 fp32)  -> W2b bf16 [16][384] row-major (12288 B)
// ---------------------------------------------------------------------------
__global__ void __launch_bounds__(256) prep_weights(const float* __restrict__ W1d,
                                                    const float* __restrict__ W2d,
                                                    u16t* __restrict__ Wt,
                                                    uint4* __restrict__ W2b) {
    int bid = blockIdx.x;
    if (bid < 32) {
        int t = bid * 256 + threadIdx.x;          // 0..8191
        int g = t >> 10, k = (t >> 7) & 7, o = t & 127;
        const float* src = W1d + (((g << 7) + o) << 6) + (k << 3);
        u16t* dst = Wt + ((((g << 3) + k) << 7) + o) * 8;
#pragma unroll
        for (int j = 0; j < 8; ++j) {
            uint32_t u = __float_as_uint(src[j]);
            uint32_t r = (u + 0x7FFFu + ((u >> 16) & 1u)) >> 16;   // RN to bf16
            dst[j] = (u16t)r;
        }
    } else {
        int idx = (bid - 32) * 256 + threadIdx.x;  // 0..767 (chunks of 8 f32)
        const float4* s = (const float4*)W2d + idx * 2;
        float4 A = s[0], B = s[1];
        uint4 p;
        p.x = pk_bf16(A.x, A.y); p.y = pk_bf16(A.z, A.w);
        p.z = pk_bf16(B.x, B.y); p.w = pk_bf16(B.z, B.w);
        W2b[idx] = p;
    }
}

// ---------------------------------------------------------------------------
// Barrier-free kernel: ONE WAVE = ONE HALF-TILE (rows u in [16h, 16h+16)).
// 8192 waves total, grid 2048 x 256 (4 independent waves/block), target
// 8 waves/SIMD = 32/CU via __launch_bounds__(256,8) (VGPR <= 64).
//  phase 2: full conv2d per wave via mfma_16x16x32 (x, W2b from global/L3)
//  phase 3: conv1d for 4 groups (g = 4h+2q+gh) + softmax; all intra-wave
//  phase 4: out rows = attn_half(16x32) . x via 24x mfma_16x16x32
// NO s_barrier anywhere; only same-wave lgkmcnt fences.
// LDS/block: 4 * (2048 ys + 1280 zs) = 13312 B.
// ---------------------------------------------------------------------------
template <bool WBF>
__global__ void __launch_bounds__(256, 8) dynamixer_fused(
    const float* __restrict__ x,
    const float* __restrict__ W2d,
    const float* __restrict__ b2d,
    const float* __restrict__ W1d,
    const float* __restrict__ b1d,
    const u16t* __restrict__ Wt,
    const u16t* __restrict__ W2b,
    float* __restrict__ out)
{
    __shared__ alignas(16) float ys[4][512];        // full y per wave
    __shared__ alignas(16) u16t zs16[4][16 * 40];   // attn half, stride 40

    const int t = threadIdx.x;
    const int wid = t >> 6, lane = t & 63;
    const int tile = blockIdx.x * 2 + (wid >> 1);    // (b,h) tile
    const int h = wid & 1;                            // half: u in [16h,16h+16)
    const float* __restrict__ xsrc = x + (size_t)tile * 12288;
    float* const ysW = ys[wid];
    u16t* const zsW = zs16[wid];

    const int g4 = lane >> 4, m = lane & 15;          // reused lane decodes
    const int gh = lane >> 5, l31 = lane & 31;

    // ---------------- phase 2: full conv2d via MFMA 16x16x32 ----------------
    {
        f32x4 c0, c1;
#pragma unroll
        for (int r = 0; r < 4; ++r) { c0[r] = 0.f; c1[r] = 0.f; }
        const float* __restrict__ xr0 = xsrc + m * 384;
        const float* __restrict__ xr1 = xsrc + (m + 16) * 384;
#pragma unroll 4
        for (int ks = 0; ks < 12; ++ks) {
            const int d0 = ks * 32 + g4 * 8;
            float4 xa = *(const float4*)(xr0 + d0);
            float4 xb = *(const float4*)(xr0 + d0 + 4);
            float4 xc = *(const float4*)(xr1 + d0);
            float4 xd = *(const float4*)(xr1 + d0 + 4);
            union { uint4 u; bf16x8 v; } b0, b1;
            b0.u.x = pk_bf16(xa.x, xa.y); b0.u.y = pk_bf16(xa.z, xa.w);
            b0.u.z = pk_bf16(xb.x, xb.y); b0.u.w = pk_bf16(xb.z, xb.w);
            b1.u.x = pk_bf16(xc.x, xc.y); b1.u.y = pk_bf16(xc.z, xc.w);
            b1.u.z = pk_bf16(xd.x, xd.y); b1.u.w = pk_bf16(xd.z, xd.w);
            bf16x8 a;
            if (WBF) {
                a = *(const bf16x8*)&W2b[m * 384 + d0];
            } else {
                const float* wf = W2d + m * 384 + d0;
                float4 wa = *(const float4*)wf, wb = *(const float4*)(wf + 4);
                union { uint4 u; bf16x8 v; } cvt;
                cvt.u.x = pk_bf16(wa.x, wa.y); cvt.u.y = pk_bf16(wa.z, wa.w);
                cvt.u.z = pk_bf16(wb.x, wb.y); cvt.u.w = pk_bf16(wb.z, wb.w);
                a = cvt.v;
            }
            c0 = __builtin_amdgcn_mfma_f32_16x16x32_bf16(a, b0.v, c0, 0, 0, 0);
            c1 = __builtin_amdgcn_mfma_f32_16x16x32_bf16(a, b1.v, c1, 0, 0, 0);
        }
        // whole wave writes all of ys: C row = e = g4*4+r, col = w = m / m+16
        float4 bb = *(const float4*)&b2d[g4 * 4];
        float bbv[4] = {bb.x, bb.y, bb.z, bb.w};
#pragma unroll
        for (int r = 0; r < 4; ++r) {
            ysW[(g4 * 4 + r) * 32 + m]      = c0[r] + bbv[r];
            ysW[(g4 * 4 + r) * 32 + 16 + m] = c1[r] + bbv[r];
        }
    }
    asm volatile("s_waitcnt lgkmcnt(0)" ::: "memory");   // ys intra-wave
    __builtin_amdgcn_sched_barrier(0);

    // ---------------- phase 3: conv1d (4 groups) + softmax ----------------
    {
        const int l = l31;
#pragma unroll
        for (int q = 0; q < 2; ++q) {
            const int g = 4 * h + 2 * q + gh;
            float2 ac2[4];
#pragma unroll
            for (int j = 0; j < 4; ++j) ac2[j] = make_float2(0.f, 0.f);
            if (WBF) {
                const uint4* __restrict__ wpt = (const uint4*)Wt + (g << 10);
#pragma unroll
                for (int k = 0; k < 8; ++k) {
                    const float2* yp = (const float2*)&ysW[(g << 6) + (k << 3)];
                    float2 y0 = yp[0], y1 = yp[1], y2 = yp[2], y3 = yp[3];
#pragma unroll
                    for (int j = 0; j < 4; ++j) {
                        uint4 wq = wpt[(k << 7) + l + (j << 5)];
                        ac2[j] += up2(wq.x) * y0;
                        ac2[j] += up2(wq.y) * y1;
                        ac2[j] += up2(wq.z) * y2;
                        ac2[j] += up2(wq.w) * y3;
                    }
                }
            } else {
#pragma unroll
                for (int k = 0; k < 8; ++k) {
                    const float2* yp = (const float2*)&ysW[(g << 6) + (k << 3)];
                    float2 y0 = yp[0], y1 = yp[1], y2 = yp[2], y3 = yp[3];
#pragma unroll
                    for (int j = 0; j < 4; ++j) {
                        const float2* wr = (const float2*)(W1d + (((g << 7) + l + (j << 5)) << 6) + (k << 3));
                        ac2[j] += wr[0] * y0;
                        ac2[j] += wr[1] * y1;
                        ac2[j] += wr[2] * y2;
                        ac2[j] += wr[3] * y3;
                    }
                }
            }
            float acc[4];
#pragma unroll
            for (int j = 0; j < 4; ++j)
                acc[j] = ac2[j].x + ac2[j].y + b1d[(g << 7) + (j << 5) + l];

            // softmax over v (= lane within 32-lane half); u16 = 4*(2q+gh)+j
#pragma unroll
            for (int j = 0; j < 4; ++j) {
                float mx = acc[j];
#pragma unroll
                for (int s = 16; s >= 1; s >>= 1) mx = fmaxf(mx, __shfl_xor(mx, s, 32));
                float p = __expf(acc[j] - mx);
                float ssum = p;
#pragma unroll
                for (int s = 16; s >= 1; s >>= 1) ssum += __shfl_xor(ssum, s, 32);
                float pv = __fdividef(p, ssum);
                zsW[(4 * (2 * q + gh) + j) * 40 + l] = (u16t)pk_bf16(pv, pv);
            }
        }
    }
    asm volatile("s_waitcnt lgkmcnt(0)" ::: "memory");   // zs intra-wave
    __builtin_amdgcn_sched_barrier(0);

    // ---------------- phase 4: out_half = attn_half . x  (24 MFMA) --------
    {
        // A frag (16x16x32): row u16 = m, k = v = g4*8 + j  -> one ds_read_b128
        bf16x8 A = *(const bf16x8*)&zsW[m * 40 + g4 * 8];
        float* __restrict__ obase = out + (size_t)tile * 12288 + (16 * h) * 384;
        const float* __restrict__ xcb = xsrc + (g4 * 8) * 384 + m;  // v-base, col m
#pragma unroll 2
        for (int i = 0; i < 24; ++i) {
            const int d0 = i * 16;
            float v8[8];
#pragma unroll
            for (int j = 0; j < 8; ++j) v8[j] = xcb[j * 384 + d0];
            union { uint4 u; bf16x8 v; } B;
            B.u.x = pk_bf16(v8[0], v8[1]); B.u.y = pk_bf16(v8[2], v8[3]);
            B.u.z = pk_bf16(v8[4], v8[5]); B.u.w = pk_bf16(v8[6], v8[7]);
            f32x4 c;
#pragma unroll
            for (int r = 0; r < 4; ++r) c[r] = 0.f;
            c = __builtin_amdgcn_mfma_f32_16x16x32_bf16(A, B.v, c, 0, 0, 0);
            // C (16x16): col = m, row = g4*4 + r
#pragma unroll
            for (int r = 0; r < 4; ++r)
                obase[(g4 * 4 + r) * 384 + d0 + m] = c[r];
        }
    }
}

// ---------------------------------------------------------------------------
extern "C" void kernel_launch(void* const* d_in, const int* in_sizes, int n_in,
                              void* d_out, int out_size, void* d_ws, size_t ws_size,
                              hipStream_t stream) {
    const float* x   = (const float*)d_in[0];
    const float* W2d = (const float*)d_in[1];
    const float* b2d = (const float*)d_in[2];
    const float* W1d = (const float*)d_in[3];
    const float* b1d = (const float*)d_in[4];
    float* out = (float*)d_out;

    const size_t wt_bytes  = 8 * 8 * 128 * 8 * sizeof(u16t);   // 131072
    const size_t w2b_bytes = 16 * 384 * sizeof(u16t);          // 12288
    if (ws_size >= wt_bytes + w2b_bytes) {
        u16t* Wt = (u16t*)d_ws;
        u16t* W2b = (u16t*)((char*)d_ws + wt_bytes);
        prep_weights<<<35, 256, 0, stream>>>(W1d, W2d, Wt, (uint4*)W2b);
        dynamixer_fused<true><<<2048, 256, 0, stream>>>(x, W2d, b2d, W1d, b1d, Wt, W2b, out);
    } else {
        dynamixer_fused<false><<<2048, 256, 0, stream>>>(x, W2d, b2d, W1d, b1d, nullptr, nullptr, out);
    }
}

// Round 15
// 90.886 us; speedup vs baseline: 2.2856x; 2.2856x over previous
//
#include <hip/hip_runtime.h>
#include <stdint.h>

typedef unsigned short u16t;
typedef __attribute__((ext_vector_type(8))) short bf16x8;
typedef __attribute__((ext_vector_type(4))) float f32x4;
typedef __attribute__((ext_vector_type(16))) float f32x16;

__device__ __forceinline__ float2 up2(uint32_t u) {
    return make_float2(__uint_as_float(u << 16), __uint_as_float(u & 0xFFFF0000u));
}
__device__ __forceinline__ uint32_t pk_bf16(float a, float b) {
    uint32_t r;
    asm("v_cvt_pk_bf16_f32 %0, %1, %2" : "=v"(r) : "v"(a), "v"(b));
    return r;   // lo16 = bf16(a) RNE, hi16 = bf16(b)
}

// pinned 16B global load: compiler cannot sink/serialize asm volatile outputs
#define GLD4(dst, addr, OFF) \
    asm volatile("global_load_dwordx4 %0, %1, off" OFF : "=&v"(dst) : "v"(addr))

// counted vmcnt wait; "memory" stops memory-op reordering, sched_barrier(0)
// stops VALU use-hoisting (rule #18).  vmcnt(N) = count of MY younger loads;
// foreign loads only make the wait more conservative (issue-ordered counter).
#define WAITV(NLIT) do {                                                   \
    asm volatile("s_waitcnt vmcnt(" #NLIT ")" ::: "memory");               \
    __builtin_amdgcn_sched_barrier(0); } while (0)

// issue 8 Wt loads (2 k-groups x 4 o-blocks), offsets k*2048 + j*512
#define WT_ISSUE8(B, A) do {                                               \
    GLD4(B[0], A, "");                GLD4(B[1], A, " offset:512");        \
    GLD4(B[2], A, " offset:1024");    GLD4(B[3], A, " offset:1536");       \
    GLD4(B[4], A, " offset:2048");    GLD4(B[5], A, " offset:2560");       \
    GLD4(B[6], A, " offset:3072");    GLD4(B[7], A, " offset:3584"); } while (0)

#define P3_PROC2(K, BUF) do {                                              \
    _Pragma("unroll")                                                      \
    for (int kk = 0; kk < 2; ++kk) {                                       \
        const float2* yp = (const float2*)&ys[(g << 6) + (((K) + kk) << 3)];\
        float2 y0 = yp[0], y1 = yp[1], y2 = yp[2], y3 = yp[3];             \
        _Pragma("unroll")                                                  \
        for (int j = 0; j < 4; ++j) {                                      \
            uint4 wq = BUF[kk * 4 + j];                                    \
            ac2[j] += up2(wq.x) * y0;                                      \
            ac2[j] += up2(wq.y) * y1;                                      \
            ac2[j] += up2(wq.z) * y2;                                      \
            ac2[j] += up2(wq.w) * y3;                                      \
        }                                                                  \
    } } while (0)

// ---------------------------------------------------------------------------
// Pre-kernel (35 blocks):
//  blocks 0-31 : W1d (1024x64 fp32) -> Wt bf16 [g][k][o][j]   (131072 B)
//  blocks 32-34: W2d (16x384 fp32)  -> W2b bf16 [16][384] row-major (12288 B)
// ---------------------------------------------------------------------------
__global__ void __launch_bounds__(256) prep_weights(const float* __restrict__ W1d,
                                                    const float* __restrict__ W2d,
                                                    u16t* __restrict__ Wt,
                                                    uint4* __restrict__ W2b) {
    int bid = blockIdx.x;
    if (bid < 32) {
        int t = bid * 256 + threadIdx.x;          // 0..8191
        int g = t >> 10, k = (t >> 7) & 7, o = t & 127;
        const float* src = W1d + (((g << 7) + o) << 6) + (k << 3);
        u16t* dst = Wt + ((((g << 3) + k) << 7) + o) * 8;
#pragma unroll
        for (int j = 0; j < 8; ++j) {
            uint32_t u = __float_as_uint(src[j]);
            uint32_t r = (u + 0x7FFFu + ((u >> 16) & 1u)) >> 16;   // RN to bf16
            dst[j] = (u16t)r;
        }
    } else {
        int idx = (bid - 32) * 256 + threadIdx.x;  // 0..767 (chunks of 8 f32)
        const float4* s = (const float4*)W2d + idx * 2;
        float4 A = s[0], B = s[1];
        uint4 p;
        p.x = pk_bf16(A.x, A.y); p.y = pk_bf16(A.z, A.w);
        p.z = pk_bf16(B.x, B.y); p.w = pk_bf16(B.z, B.w);
        W2b[idx] = p;
    }
}

// ---------------------------------------------------------------------------
// Fused kernel (R11 structure — best known, 109.9 us):
//  phase 1: 12 asm global_load_dwordx4 (pinned, all in flight) -> counted
//           vmcnt -> pk_bf16 -> ds_write_b128;  bf16 tile xs16[32][392]
//  phase 2: y = W2d.x^T via mfma_16x16x32_bf16 (per-wave dup, e-slice write)
//  phase 3: conv1d with double-buffered asm Wt batches + softmax -> zs16
//  phase 4: out = attn.x via mfma_32x32x16_bf16; C-stores NON-TEMPORAL so
//           the 201MB write stream does not evict x from Infinity Cache.
// LDS: 25088 + 2048 + 2560 = 29696 B.  Barriers: 2.
// ---------------------------------------------------------------------------
template <bool WBF>
__global__ void __launch_bounds__(256, 4) dynamixer_fused(
    const float* __restrict__ x,
    const float* __restrict__ W2d,
    const float* __restrict__ b2d,
    const float* __restrict__ W1d,
    const float* __restrict__ b1d,
    const u16t* __restrict__ Wt,
    const u16t* __restrict__ W2b,
    float* __restrict__ out)
{
    __shared__ u16t xs16[32 * 392];             // bf16 x tile, row stride 392
    __shared__ alignas(16) float ys[512];       // y, flat e*32+w
    __shared__ alignas(16) u16t zs16[32 * 40];  // attn bf16, row stride 40

    const int t = threadIdx.x;
    const int blk = blockIdx.x;                           // b*32 + h
    const float* __restrict__ xsrc = x + (size_t)blk * 12288;
    const int wid = t >> 6, lane = t & 63;
    const int g2 = lane >> 5, l31 = lane & 31;
    const int g = t >> 5, l = t & 31;

    // ---------------- phase 1: asm-pinned stage -> bf16 LDS ----------------
    {
        float4 st[12];
        uint64_t a = (uint64_t)(uintptr_t)xsrc + (uint32_t)(t * 32);
#pragma unroll
        for (int k = 0; k < 6; ++k) {
            GLD4(st[2 * k],     a, "");
            GLD4(st[2 * k + 1], a, " offset:16");
            a += 8192;                       // next pair: p += 256
        }
        // progressive consume: pair k needs my loads 2k,2k+1 -> vmcnt(10-2k)
#pragma unroll
        for (int k = 0; k < 6; ++k) {
            switch (k) {
                case 0: WAITV(10); break;
                case 1: WAITV(8);  break;
                case 2: WAITV(6);  break;
                case 3: WAITV(4);  break;
                case 4: WAITV(2);  break;
                default: WAITV(0); break;
            }
            int p = t + (k << 8);
            int row = p / 48, c = p - row * 48;
            uint4 pk;
            pk.x = pk_bf16(st[2 * k].x,     st[2 * k].y);
            pk.y = pk_bf16(st[2 * k].z,     st[2 * k].w);
            pk.z = pk_bf16(st[2 * k + 1].x, st[2 * k + 1].y);
            pk.w = pk_bf16(st[2 * k + 1].z, st[2 * k + 1].w);
            *(uint4*)&xs16[row * 392 + c * 8] = pk;
        }
    }
    asm volatile("s_waitcnt lgkmcnt(0)" ::: "memory");
    __builtin_amdgcn_s_barrier();
    asm volatile("" ::: "memory");
    __builtin_amdgcn_sched_barrier(0);

    // ---------------- phase 2: conv2d via MFMA 16x16x32 ----------------
    {
        const int g4 = lane >> 4, m = lane & 15;          // A row=e, B col=w=m
        f32x4 c0, c1;
#pragma unroll
        for (int r = 0; r < 4; ++r) { c0[r] = 0.f; c1[r] = 0.f; }
        __builtin_amdgcn_s_setprio(1);
#pragma unroll 4
        for (int ks = 0; ks < 12; ++ks) {
            const int d0 = ks * 32 + g4 * 8;
            bf16x8 a;
            if (WBF) {
                a = *(const bf16x8*)&W2b[m * 384 + d0];
            } else {
                const float* wf = W2d + m * 384 + d0;
                float4 wa = *(const float4*)wf, wb = *(const float4*)(wf + 4);
                union { uint4 u; bf16x8 v; } cvt;
                cvt.u.x = pk_bf16(wa.x, wa.y); cvt.u.y = pk_bf16(wa.z, wa.w);
                cvt.u.z = pk_bf16(wb.x, wb.y); cvt.u.w = pk_bf16(wb.z, wb.w);
                a = cvt.v;
            }
            bf16x8 b0 = *(const bf16x8*)&xs16[m * 392 + d0];
            bf16x8 b1 = *(const bf16x8*)&xs16[(m + 16) * 392 + d0];
            c0 = __builtin_amdgcn_mfma_f32_16x16x32_bf16(a, b0, c0, 0, 0, 0);
            c1 = __builtin_amdgcn_mfma_f32_16x16x32_bf16(a, b1, c1, 0, 0, 0);
        }
        __builtin_amdgcn_s_setprio(0);
        // write only this wave's e-slice [4*wid, 4*wid+4): C row=g4*4+r, col=m
        if (g4 == wid) {
            float4 bb = *(const float4*)&b2d[wid * 4];
            float bbv[4] = {bb.x, bb.y, bb.z, bb.w};
#pragma unroll
            for (int r = 0; r < 4; ++r) {
                ys[(4 * wid + r) * 32 + m]      = c0[r] + bbv[r];
                ys[(4 * wid + r) * 32 + 16 + m] = c1[r] + bbv[r];
            }
        }
    }
    asm volatile("s_waitcnt lgkmcnt(0)" ::: "memory");    // ys visible intra-wave
    __builtin_amdgcn_sched_barrier(0);

    // ---------------- phase 3: conv1d (asm dbuf Wt) + softmax ----------
    {
        float2 ac2[4];
#pragma unroll
        for (int j = 0; j < 4; ++j) ac2[j] = make_float2(0.f, 0.f);
        if (WBF) {
            uint4 bufA[8], bufB[8];
            uint64_t wa = (uint64_t)(uintptr_t)Wt + ((uint32_t)g << 14)
                        + ((uint32_t)l << 4);
            WT_ISSUE8(bufA, wa);  wa += 4096;      // k = 0,1
            WT_ISSUE8(bufB, wa);  wa += 4096;      // k = 2,3
            WAITV(8);                               // bufA ready (8 younger)
            P3_PROC2(0, bufA);
            WT_ISSUE8(bufA, wa);  wa += 4096;      // k = 4,5
            WAITV(8);                               // bufB ready
            P3_PROC2(2, bufB);
            WT_ISSUE8(bufB, wa);                    // k = 6,7
            WAITV(8);                               // bufA (k=4,5) ready
            P3_PROC2(4, bufA);
            WAITV(0);                               // bufB (k=6,7) ready
            P3_PROC2(6, bufB);
        } else {
#pragma unroll
            for (int k = 0; k < 8; ++k) {
                const float2* yp = (const float2*)&ys[(g << 6) + (k << 3)];
                float2 y0 = yp[0], y1 = yp[1], y2 = yp[2], y3 = yp[3];
#pragma unroll
                for (int j = 0; j < 4; ++j) {
                    const float2* wr = (const float2*)(W1d + (((g << 7) + l + (j << 5)) << 6) + (k << 3));
                    ac2[j] += wr[0] * y0;
                    ac2[j] += wr[1] * y1;
                    ac2[j] += wr[2] * y2;
                    ac2[j] += wr[3] * y3;
                }
            }
        }
        float acc[4];
#pragma unroll
        for (int j = 0; j < 4; ++j)
            acc[j] = ac2[j].x + ac2[j].y + b1d[(g << 7) + (j << 5) + l];

        // softmax over v (= lane within 32-lane group), row u = 4g+j
#pragma unroll
        for (int j = 0; j < 4; ++j) {
            float mx = acc[j];
#pragma unroll
            for (int s = 16; s >= 1; s >>= 1) mx = fmaxf(mx, __shfl_xor(mx, s, 32));
            float p = __expf(acc[j] - mx);
            float ssum = p;
#pragma unroll
            for (int s = 16; s >= 1; s >>= 1) ssum += __shfl_xor(ssum, s, 32);
            float pv = __fdividef(p, ssum);
            zs16[((g << 2) + j) * 40 + l] = (u16t)pk_bf16(pv, pv);
        }
    }
    asm volatile("s_waitcnt lgkmcnt(0)" ::: "memory");
    __builtin_amdgcn_s_barrier();
    asm volatile("" ::: "memory");
    __builtin_amdgcn_sched_barrier(0);

    // ---------------- phase 4: out = attn . x via MFMA 32x32x16 ----------
    {
        // A frags: attn[u = l31][k = g2*8 + j (+16)]
        bf16x8 A0 = *(const bf16x8*)&zs16[l31 * 40 + g2 * 8];
        bf16x8 A1 = *(const bf16x8*)&zs16[l31 * 40 + 16 + g2 * 8];
        float* __restrict__ obase = out + (size_t)blk * 12288;
#pragma unroll
        for (int i = 0; i < 3; ++i) {
            const int d = wid * 96 + i * 32 + l31;
            const u16t* __restrict__ xc = xs16 + d;
            bf16x8 B0, B1;
#pragma unroll
            for (int j = 0; j < 8; ++j) {
                B0[j] = (short)xc[(g2 * 8 + j) * 392];
                B1[j] = (short)xc[(16 + g2 * 8 + j) * 392];
            }
            f32x16 acc16;
#pragma unroll
            for (int r = 0; r < 16; ++r) acc16[r] = 0.f;
            __builtin_amdgcn_s_setprio(1);
            acc16 = __builtin_amdgcn_mfma_f32_32x32x16_bf16(A0, B0, acc16, 0, 0, 0);
            acc16 = __builtin_amdgcn_mfma_f32_32x32x16_bf16(A1, B1, acc16, 0, 0, 0);
            __builtin_amdgcn_s_setprio(0);
            // NON-TEMPORAL stores: don't let the 201MB out-stream evict x
            // from L3 -- x stays Infinity-Cache-resident across replays.
#pragma unroll
            for (int r = 0; r < 16; ++r) {
                const int u = (r & 3) + 8 * (r >> 2) + 4 * g2;
                __builtin_nontemporal_store(acc16[r], &obase[u * 384 + d]);
            }
        }
    }
}

// ---------------------------------------------------------------------------
extern "C" void kernel_launch(void* const* d_in, const int* in_sizes, int n_in,
                              void* d_out, int out_size, void* d_ws, size_t ws_size,
                              hipStream_t stream) {
    const float* x   = (const float*)d_in[0];
    const float* W2d = (const float*)d_in[1];
    const float* b2d = (const float*)d_in[2];
    const float* W1d = (const float*)d_in[3];
    const float* b1d = (const float*)d_in[4];
    float* out = (float*)d_out;

    const size_t wt_bytes  = 8 * 8 * 128 * 8 * sizeof(u16t);   // 131072
    const size_t w2b_bytes = 16 * 384 * sizeof(u16t);          // 12288
    if (ws_size >= wt_bytes + w2b_bytes) {
        u16t* Wt = (u16t*)d_ws;
        u16t* W2b = (u16t*)((char*)d_ws + wt_bytes);
        prep_weights<<<35, 256, 0, stream>>>(W1d, W2d, Wt, (uint4*)W2b);
        dynamixer_fused<true><<<4096, 256, 0, stream>>>(x, W2d, b2d, W1d, b1d, Wt, W2b, out);
    } else {
        dynamixer_fused<false><<<4096, 256, 0, stream>>>(x, W2d, b2d, W1d, b1d, nullptr, nullptr, out);
    }
}

// Round 16
// 89.350 us; speedup vs baseline: 2.3249x; 1.0172x over previous
//
#include <hip/hip_runtime.h>
#include <stdint.h>

typedef unsigned short u16t;
typedef __attribute__((ext_vector_type(8))) short bf16x8;
typedef __attribute__((ext_vector_type(4))) float f32x4;
typedef __attribute__((ext_vector_type(16))) float f32x16;

__device__ __forceinline__ float2 up2(uint32_t u) {
    return make_float2(__uint_as_float(u << 16), __uint_as_float(u & 0xFFFF0000u));
}
__device__ __forceinline__ uint32_t pk_bf16(float a, float b) {
    uint32_t r;
    asm("v_cvt_pk_bf16_f32 %0, %1, %2" : "=v"(r) : "v"(a), "v"(b));
    return r;   // lo16 = bf16(a) RNE, hi16 = bf16(b)
}

// pinned 16B global load: compiler cannot sink/serialize asm volatile outputs
#define GLD4(dst, addr, OFF) \
    asm volatile("global_load_dwordx4 %0, %1, off" OFF : "=&v"(dst) : "v"(addr))

// counted vmcnt wait; "memory" stops memory-op reordering, sched_barrier(0)
// stops VALU use-hoisting (rule #18).  vmcnt(N) = count of MY younger loads;
// foreign loads only make the wait more conservative (issue-ordered counter).
#define WAITV(NLIT) do {                                                   \
    asm volatile("s_waitcnt vmcnt(" #NLIT ")" ::: "memory");               \
    __builtin_amdgcn_sched_barrier(0); } while (0)

// issue 8 Wt loads (2 k-groups x 4 o-blocks), offsets k*2048 + j*512
#define WT_ISSUE8(B, A) do {                                               \
    GLD4(B[0], A, "");                GLD4(B[1], A, " offset:512");        \
    GLD4(B[2], A, " offset:1024");    GLD4(B[3], A, " offset:1536");       \
    GLD4(B[4], A, " offset:2048");    GLD4(B[5], A, " offset:2560");       \
    GLD4(B[6], A, " offset:3072");    GLD4(B[7], A, " offset:3584"); } while (0)

#define P3_PROC2(K, BUF) do {                                              \
    _Pragma("unroll")                                                      \
    for (int kk = 0; kk < 2; ++kk) {                                       \
        const float2* yp = (const float2*)&ys[(g << 6) + (((K) + kk) << 3)];\
        float2 y0 = yp[0], y1 = yp[1], y2 = yp[2], y3 = yp[3];             \
        _Pragma("unroll")                                                  \
        for (int j = 0; j < 4; ++j) {                                      \
            uint4 wq = BUF[kk * 4 + j];                                    \
            ac2[j] += up2(wq.x) * y0;                                      \
            ac2[j] += up2(wq.y) * y1;                                      \
            ac2[j] += up2(wq.z) * y2;                                      \
            ac2[j] += up2(wq.w) * y3;                                      \
        }                                                                  \
    } } while (0)

// ---------------------------------------------------------------------------
// Pre-kernel (35 blocks):
//  blocks 0-31 : W1d (1024x64 fp32) -> Wt bf16 [g][k][o][j]   (131072 B)
//  blocks 32-34: W2d (16x384 fp32)  -> W2b bf16 [16][384] row-major (12288 B)
// ---------------------------------------------------------------------------
__global__ void __launch_bounds__(256) prep_weights(const float* __restrict__ W1d,
                                                    const float* __restrict__ W2d,
                                                    u16t* __restrict__ Wt,
                                                    uint4* __restrict__ W2b) {
    int bid = blockIdx.x;
    if (bid < 32) {
        int t = bid * 256 + threadIdx.x;          // 0..8191
        int g = t >> 10, k = (t >> 7) & 7, o = t & 127;
        const float* src = W1d + (((g << 7) + o) << 6) + (k << 3);
        u16t* dst = Wt + ((((g << 3) + k) << 7) + o) * 8;
#pragma unroll
        for (int j = 0; j < 8; ++j) {
            uint32_t u = __float_as_uint(src[j]);
            uint32_t r = (u + 0x7FFFu + ((u >> 16) & 1u)) >> 16;   // RN to bf16
            dst[j] = (u16t)r;
        }
    } else {
        int idx = (bid - 32) * 256 + threadIdx.x;  // 0..767 (chunks of 8 f32)
        const float4* s = (const float4*)W2d + idx * 2;
        float4 A = s[0], B = s[1];
        uint4 p;
        p.x = pk_bf16(A.x, A.y); p.y = pk_bf16(A.z, A.w);
        p.z = pk_bf16(B.x, B.y); p.w = pk_bf16(B.z, B.w);
        W2b[idx] = p;
    }
}

// ---------------------------------------------------------------------------
// Fused kernel (R15 structure + 5 blocks/CU):
//  phase 1: 12 asm global_load_dwordx4 (pinned, all in flight) -> counted
//           vmcnt -> pk_bf16 -> ds_write_b128;  bf16 tile xs16[32][392]
//  phase 2: y = W2d.x^T via mfma_16x16x32_bf16 (per-wave dup, e-slice write)
//  phase 3: conv1d with double-buffered asm Wt batches + softmax -> zs16
//  phase 4: out = attn.x via mfma_32x32x16_bf16; NON-TEMPORAL C-stores so
//           the 201MB write stream does not evict x from Infinity Cache.
// LDS: 25088 + 2048 + 2560 = 29696 B -> 5 blocks/CU (148 KB of 160 KB).
// ---------------------------------------------------------------------------
template <bool WBF>
__global__ void __launch_bounds__(256, 5) dynamixer_fused(
    const float* __restrict__ x,
    const float* __restrict__ W2d,
    const float* __restrict__ b2d,
    const float* __restrict__ W1d,
    const float* __restrict__ b1d,
    const u16t* __restrict__ Wt,
    const u16t* __restrict__ W2b,
    float* __restrict__ out)
{
    __shared__ u16t xs16[32 * 392];             // bf16 x tile, row stride 392
    __shared__ alignas(16) float ys[512];       // y, flat e*32+w
    __shared__ alignas(16) u16t zs16[32 * 40];  // attn bf16, row stride 40

    const int t = threadIdx.x;
    const int blk = blockIdx.x;                           // b*32 + h
    const float* __restrict__ xsrc = x + (size_t)blk * 12288;
    const int wid = t >> 6, lane = t & 63;
    const int g2 = lane >> 5, l31 = lane & 31;
    const int g = t >> 5, l = t & 31;

    // ---------------- phase 1: asm-pinned stage -> bf16 LDS ----------------
    {
        float4 st[12];
        uint64_t a = (uint64_t)(uintptr_t)xsrc + (uint32_t)(t * 32);
#pragma unroll
        for (int k = 0; k < 6; ++k) {
            GLD4(st[2 * k],     a, "");
            GLD4(st[2 * k + 1], a, " offset:16");
            a += 8192;                       // next pair: p += 256
        }
        // progressive consume: pair k needs my loads 2k,2k+1 -> vmcnt(10-2k)
#pragma unroll
        for (int k = 0; k < 6; ++k) {
            switch (k) {
                case 0: WAITV(10); break;
                case 1: WAITV(8);  break;
                case 2: WAITV(6);  break;
                case 3: WAITV(4);  break;
                case 4: WAITV(2);  break;
                default: WAITV(0); break;
            }
            int p = t + (k << 8);
            int row = p / 48, c = p - row * 48;
            uint4 pk;
            pk.x = pk_bf16(st[2 * k].x,     st[2 * k].y);
            pk.y = pk_bf16(st[2 * k].z,     st[2 * k].w);
            pk.z = pk_bf16(st[2 * k + 1].x, st[2 * k + 1].y);
            pk.w = pk_bf16(st[2 * k + 1].z, st[2 * k + 1].w);
            *(uint4*)&xs16[row * 392 + c * 8] = pk;
        }
    }
    asm volatile("s_waitcnt lgkmcnt(0)" ::: "memory");
    __builtin_amdgcn_s_barrier();
    asm volatile("" ::: "memory");
    __builtin_amdgcn_sched_barrier(0);

    // ---------------- phase 2: conv2d via MFMA 16x16x32 ----------------
    {
        const int g4 = lane >> 4, m = lane & 15;          // A row=e, B col=w=m
        f32x4 c0, c1;
#pragma unroll
        for (int r = 0; r < 4; ++r) { c0[r] = 0.f; c1[r] = 0.f; }
        __builtin_amdgcn_s_setprio(1);
#pragma unroll 4
        for (int ks = 0; ks < 12; ++ks) {
            const int d0 = ks * 32 + g4 * 8;
            bf16x8 a;
            if (WBF) {
                a = *(const bf16x8*)&W2b[m * 384 + d0];
            } else {
                const float* wf = W2d + m * 384 + d0;
                float4 wa = *(const float4*)wf, wb = *(const float4*)(wf + 4);
                union { uint4 u; bf16x8 v; } cvt;
                cvt.u.x = pk_bf16(wa.x, wa.y); cvt.u.y = pk_bf16(wa.z, wa.w);
                cvt.u.z = pk_bf16(wb.x, wb.y); cvt.u.w = pk_bf16(wb.z, wb.w);
                a = cvt.v;
            }
            bf16x8 b0 = *(const bf16x8*)&xs16[m * 392 + d0];
            bf16x8 b1 = *(const bf16x8*)&xs16[(m + 16) * 392 + d0];
            c0 = __builtin_amdgcn_mfma_f32_16x16x32_bf16(a, b0, c0, 0, 0, 0);
            c1 = __builtin_amdgcn_mfma_f32_16x16x32_bf16(a, b1, c1, 0, 0, 0);
        }
        __builtin_amdgcn_s_setprio(0);
        // write only this wave's e-slice [4*wid, 4*wid+4): C row=g4*4+r, col=m
        if (g4 == wid) {
            float4 bb = *(const float4*)&b2d[wid * 4];
            float bbv[4] = {bb.x, bb.y, bb.z, bb.w};
#pragma unroll
            for (int r = 0; r < 4; ++r) {
                ys[(4 * wid + r) * 32 + m]      = c0[r] + bbv[r];
                ys[(4 * wid + r) * 32 + 16 + m] = c1[r] + bbv[r];
            }
        }
    }
    asm volatile("s_waitcnt lgkmcnt(0)" ::: "memory");    // ys visible intra-wave
    __builtin_amdgcn_sched_barrier(0);

    // ---------------- phase 3: conv1d (asm dbuf Wt) + softmax ----------
    {
        float2 ac2[4];
#pragma unroll
        for (int j = 0; j < 4; ++j) ac2[j] = make_float2(0.f, 0.f);
        if (WBF) {
            uint4 bufA[8], bufB[8];
            uint64_t wa = (uint64_t)(uintptr_t)Wt + ((uint32_t)g << 14)
                        + ((uint32_t)l << 4);
            WT_ISSUE8(bufA, wa);  wa += 4096;      // k = 0,1
            WT_ISSUE8(bufB, wa);  wa += 4096;      // k = 2,3
            WAITV(8);                               // bufA ready (8 younger)
            P3_PROC2(0, bufA);
            WT_ISSUE8(bufA, wa);  wa += 4096;      // k = 4,5
            WAITV(8);                               // bufB ready
            P3_PROC2(2, bufB);
            WT_ISSUE8(bufB, wa);                    // k = 6,7
            WAITV(8);                               // bufA (k=4,5) ready
            P3_PROC2(4, bufA);
            WAITV(0);                               // bufB (k=6,7) ready
            P3_PROC2(6, bufB);
        } else {
#pragma unroll
            for (int k = 0; k < 8; ++k) {
                const float2* yp = (const float2*)&ys[(g << 6) + (k << 3)];
                float2 y0 = yp[0], y1 = yp[1], y2 = yp[2], y3 = yp[3];
#pragma unroll
                for (int j = 0; j < 4; ++j) {
                    const float2* wr = (const float2*)(W1d + (((g << 7) + l + (j << 5)) << 6) + (k << 3));
                    ac2[j] += wr[0] * y0;
                    ac2[j] += wr[1] * y1;
                    ac2[j] += wr[2] * y2;
                    ac2[j] += wr[3] * y3;
                }
            }
        }
        float acc[4];
#pragma unroll
        for (int j = 0; j < 4; ++j)
            acc[j] = ac2[j].x + ac2[j].y + b1d[(g << 7) + (j << 5) + l];

        // softmax over v (= lane within 32-lane group), row u = 4g+j
#pragma unroll
        for (int j = 0; j < 4; ++j) {
            float mx = acc[j];
#pragma unroll
            for (int s = 16; s >= 1; s >>= 1) mx = fmaxf(mx, __shfl_xor(mx, s, 32));
            float p = __expf(acc[j] - mx);
            float ssum = p;
#pragma unroll
            for (int s = 16; s >= 1; s >>= 1) ssum += __shfl_xor(ssum, s, 32);
            float pv = __fdividef(p, ssum);
            zs16[((g << 2) + j) * 40 + l] = (u16t)pk_bf16(pv, pv);
        }
    }
    asm volatile("s_waitcnt lgkmcnt(0)" ::: "memory");
    __builtin_amdgcn_s_barrier();
    asm volatile("" ::: "memory");
    __builtin_amdgcn_sched_barrier(0);

    // ---------------- phase 4: out = attn . x via MFMA 32x32x16 ----------
    {
        // A frags: attn[u = l31][k = g2*8 + j (+16)]
        bf16x8 A0 = *(const bf16x8*)&zs16[l31 * 40 + g2 * 8];
        bf16x8 A1 = *(const bf16x8*)&zs16[l31 * 40 + 16 + g2 * 8];
        float* __restrict__ obase = out + (size_t)blk * 12288;
#pragma unroll
        for (int i = 0; i < 3; ++i) {
            const int d = wid * 96 + i * 32 + l31;
            const u16t* __restrict__ xc = xs16 + d;
            bf16x8 B0, B1;
#pragma unroll
            for (int j = 0; j < 8; ++j) {
                B0[j] = (short)xc[(g2 * 8 + j) * 392];
                B1[j] = (short)xc[(16 + g2 * 8 + j) * 392];
            }
            f32x16 acc16;
#pragma unroll
            for (int r = 0; r < 16; ++r) acc16[r] = 0.f;
            __builtin_amdgcn_s_setprio(1);
            acc16 = __builtin_amdgcn_mfma_f32_32x32x16_bf16(A0, B0, acc16, 0, 0, 0);
            acc16 = __builtin_amdgcn_mfma_f32_32x32x16_bf16(A1, B1, acc16, 0, 0, 0);
            __builtin_amdgcn_s_setprio(0);
            // NON-TEMPORAL stores: don't let the 201MB out-stream evict x
            // from L3 -- x stays Infinity-Cache-resident across replays.
#pragma unroll
            for (int r = 0; r < 16; ++r) {
                const int u = (r & 3) + 8 * (r >> 2) + 4 * g2;
                __builtin_nontemporal_store(acc16[r], &obase[u * 384 + d]);
            }
        }
    }
}

// ---------------------------------------------------------------------------
extern "C" void kernel_launch(void* const* d_in, const int* in_sizes, int n_in,
                              void* d_out, int out_size, void* d_ws, size_t ws_size,
                              hipStream_t stream) {
    const float* x   = (const float*)d_in[0];
    const float* W2d = (const float*)d_in[1];
    const float* b2d = (const float*)d_in[2];
    const float* W1d = (const float*)d_in[3];
    const float* b1d = (const float*)d_in[4];
    float* out = (float*)d_out;

    const size_t wt_bytes  = 8 * 8 * 128 * 8 * sizeof(u16t);   // 131072
    const size_t w2b_bytes = 16 * 384 * sizeof(u16t);          // 12288
    if (ws_size >= wt_bytes + w2b_bytes) {
        u16t* Wt = (u16t*)d_ws;
        u16t* W2b = (u16t*)((char*)d_ws + wt_bytes);
        prep_weights<<<35, 256, 0, stream>>>(W1d, W2d, Wt, (uint4*)W2b);
        dynamixer_fused<true><<<4096, 256, 0, stream>>>(x, W2d, b2d, W1d, b1d, Wt, W2b, out);
    } else {
        dynamixer_fused<false><<<4096, 256, 0, stream>>>(x, W2d, b2d, W1d, b1d, nullptr, nullptr, out);
    }
}

// Round 17
// 86.075 us; speedup vs baseline: 2.4133x; 1.0381x over previous
//
#include <hip/hip_runtime.h>
#include <stdint.h>

typedef unsigned short u16t;
typedef __attribute__((ext_vector_type(8))) short bf16x8;
typedef __attribute__((ext_vector_type(4))) float f32x4;
typedef __attribute__((ext_vector_type(16))) float f32x16;

__device__ __forceinline__ float2 up2(uint32_t u) {
    return make_float2(__uint_as_float(u << 16), __uint_as_float(u & 0xFFFF0000u));
}
__device__ __forceinline__ uint32_t pk_bf16(float a, float b) {
    uint32_t r;
    asm("v_cvt_pk_bf16_f32 %0, %1, %2" : "=v"(r) : "v"(a), "v"(b));
    return r;   // lo16 = bf16(a) RNE, hi16 = bf16(b)
}

// pinned 16B global load: compiler cannot sink/serialize asm volatile outputs
#define GLD4(dst, addr, OFF) \
    asm volatile("global_load_dwordx4 %0, %1, off" OFF : "=&v"(dst) : "v"(addr))

// counted vmcnt wait; "memory" stops memory-op reordering, sched_barrier(0)
// stops VALU use-hoisting (rule #18).  vmcnt(N) = count of MY younger loads;
// foreign loads only make the wait more conservative (issue-ordered counter).
#define WAITV(NLIT) do {                                                   \
    asm volatile("s_waitcnt vmcnt(" #NLIT ")" ::: "memory");               \
    __builtin_amdgcn_sched_barrier(0); } while (0)

// issue 8 Wt loads (2 k-groups x 4 o-blocks), offsets k*2048 + j*512
#define WT_ISSUE8(B, A) do {                                               \
    GLD4(B[0], A, "");                GLD4(B[1], A, " offset:512");        \
    GLD4(B[2], A, " offset:1024");    GLD4(B[3], A, " offset:1536");       \
    GLD4(B[4], A, " offset:2048");    GLD4(B[5], A, " offset:2560");       \
    GLD4(B[6], A, " offset:3072");    GLD4(B[7], A, " offset:3584"); } while (0)

#define P3_PROC2(K, BUF) do {                                              \
    _Pragma("unroll")                                                      \
    for (int kk = 0; kk < 2; ++kk) {                                       \
        const float2* yp = (const float2*)&ys[(g << 6) + (((K) + kk) << 3)];\
        float2 y0 = yp[0], y1 = yp[1], y2 = yp[2], y3 = yp[3];             \
        _Pragma("unroll")                                                  \
        for (int j = 0; j < 4; ++j) {                                      \
            uint4 wq = BUF[kk * 4 + j];                                    \
            ac2[j] += up2(wq.x) * y0;                                      \
            ac2[j] += up2(wq.y) * y1;                                      \
            ac2[j] += up2(wq.z) * y2;                                      \
            ac2[j] += up2(wq.w) * y3;                                      \
        }                                                                  \
    } } while (0)

// ---------------------------------------------------------------------------
// Pre-kernel (35 blocks):
//  blocks 0-31 : W1d (1024x64 fp32) -> Wt bf16 [g][k][o][j]   (131072 B)
//  blocks 32-34: W2d (16x384 fp32)  -> W2b bf16 [16][384] row-major (12288 B)
// ---------------------------------------------------------------------------
__global__ void __launch_bounds__(256) prep_weights(const float* __restrict__ W1d,
                                                    const float* __restrict__ W2d,
                                                    u16t* __restrict__ Wt,
                                                    uint4* __restrict__ W2b) {
    int bid = blockIdx.x;
    if (bid < 32) {
        int t = bid * 256 + threadIdx.x;          // 0..8191
        int g = t >> 10, k = (t >> 7) & 7, o = t & 127;
        const float* src = W1d + (((g << 7) + o) << 6) + (k << 3);
        u16t* dst = Wt + ((((g << 3) + k) << 7) + o) * 8;
#pragma unroll
        for (int j = 0; j < 8; ++j) {
            uint32_t u = __float_as_uint(src[j]);
            uint32_t r = (u + 0x7FFFu + ((u >> 16) & 1u)) >> 16;   // RN to bf16
            dst[j] = (u16t)r;
        }
    } else {
        int idx = (bid - 32) * 256 + threadIdx.x;  // 0..767 (chunks of 8 f32)
        const float4* s = (const float4*)W2d + idx * 2;
        float4 A = s[0], B = s[1];
        uint4 p;
        p.x = pk_bf16(A.x, A.y); p.y = pk_bf16(A.z, A.w);
        p.z = pk_bf16(B.x, B.y); p.w = pk_bf16(B.z, B.w);
        W2b[idx] = p;
    }
}

// ---------------------------------------------------------------------------
// Fused kernel (R16 + early Wt bufA prefetch):
//  phase 1: 12 asm global_load_dwordx4 (pinned) -> counted vmcnt ->
//           pk_bf16 -> ds_write_b128;  bf16 tile xs16[32][392]
//  phase 1.5: issue Wt bufA (8 loads) -- L2 latency hides under phase 2
//  phase 2: y = W2d.x^T via mfma_16x16x32_bf16 (per-wave dup, e-slice write)
//  phase 3: conv1d with double-buffered asm Wt batches + softmax -> zs16
//  phase 4: out = attn.x via mfma_32x32x16_bf16; NON-TEMPORAL C-stores so
//           the 201MB write stream does not evict x from Infinity Cache.
// LDS: 25088 + 2048 + 2560 = 29696 B -> 5 blocks/CU.
// ---------------------------------------------------------------------------
template <bool WBF>
__global__ void __launch_bounds__(256, 5) dynamixer_fused(
    const float* __restrict__ x,
    const float* __restrict__ W2d,
    const float* __restrict__ b2d,
    const float* __restrict__ W1d,
    const float* __restrict__ b1d,
    const u16t* __restrict__ Wt,
    const u16t* __restrict__ W2b,
    float* __restrict__ out)
{
    __shared__ u16t xs16[32 * 392];             // bf16 x tile, row stride 392
    __shared__ alignas(16) float ys[512];       // y, flat e*32+w
    __shared__ alignas(16) u16t zs16[32 * 40];  // attn bf16, row stride 40

    const int t = threadIdx.x;
    const int blk = blockIdx.x;                           // b*32 + h
    const float* __restrict__ xsrc = x + (size_t)blk * 12288;
    const int wid = t >> 6, lane = t & 63;
    const int g2 = lane >> 5, l31 = lane & 31;
    const int g = t >> 5, l = t & 31;

    // ---------------- phase 1: asm-pinned stage -> bf16 LDS ----------------
    {
        float4 st[12];
        uint64_t a = (uint64_t)(uintptr_t)xsrc + (uint32_t)(t * 32);
#pragma unroll
        for (int k = 0; k < 6; ++k) {
            GLD4(st[2 * k],     a, "");
            GLD4(st[2 * k + 1], a, " offset:16");
            a += 8192;                       // next pair: p += 256
        }
        // progressive consume: pair k needs my loads 2k,2k+1 -> vmcnt(10-2k)
#pragma unroll
        for (int k = 0; k < 6; ++k) {
            switch (k) {
                case 0: WAITV(10); break;
                case 1: WAITV(8);  break;
                case 2: WAITV(6);  break;
                case 3: WAITV(4);  break;
                case 4: WAITV(2);  break;
                default: WAITV(0); break;
            }
            int p = t + (k << 8);
            int row = p / 48, c = p - row * 48;
            uint4 pk;
            pk.x = pk_bf16(st[2 * k].x,     st[2 * k].y);
            pk.y = pk_bf16(st[2 * k].z,     st[2 * k].w);
            pk.z = pk_bf16(st[2 * k + 1].x, st[2 * k + 1].y);
            pk.w = pk_bf16(st[2 * k + 1].z, st[2 * k + 1].w);
            *(uint4*)&xs16[row * 392 + c * 8] = pk;
        }
    }

    // ---------------- phase 1.5: early Wt bufA prefetch ----------------
    uint4 bufA[8], bufB[8];
    uint64_t wa = (uint64_t)(uintptr_t)Wt + ((uint32_t)g << 14)
                + ((uint32_t)l << 4);
    if (WBF) {
        WT_ISSUE8(bufA, wa);  wa += 4096;          // k = 0,1 — fly over p2
    }

    asm volatile("s_waitcnt lgkmcnt(0)" ::: "memory");
    __builtin_amdgcn_s_barrier();
    asm volatile("" ::: "memory");
    __builtin_amdgcn_sched_barrier(0);

    // ---------------- phase 2: conv2d via MFMA 16x16x32 ----------------
    {
        const int g4 = lane >> 4, m = lane & 15;          // A row=e, B col=w=m
        f32x4 c0, c1;
#pragma unroll
        for (int r = 0; r < 4; ++r) { c0[r] = 0.f; c1[r] = 0.f; }
        __builtin_amdgcn_s_setprio(1);
#pragma unroll 4
        for (int ks = 0; ks < 12; ++ks) {
            const int d0 = ks * 32 + g4 * 8;
            bf16x8 a;
            if (WBF) {
                a = *(const bf16x8*)&W2b[m * 384 + d0];
            } else {
                const float* wf = W2d + m * 384 + d0;
                float4 wa4 = *(const float4*)wf, wb4 = *(const float4*)(wf + 4);
                union { uint4 u; bf16x8 v; } cvt;
                cvt.u.x = pk_bf16(wa4.x, wa4.y); cvt.u.y = pk_bf16(wa4.z, wa4.w);
                cvt.u.z = pk_bf16(wb4.x, wb4.y); cvt.u.w = pk_bf16(wb4.z, wb4.w);
                a = cvt.v;
            }
            bf16x8 b0 = *(const bf16x8*)&xs16[m * 392 + d0];
            bf16x8 b1 = *(const bf16x8*)&xs16[(m + 16) * 392 + d0];
            c0 = __builtin_amdgcn_mfma_f32_16x16x32_bf16(a, b0, c0, 0, 0, 0);
            c1 = __builtin_amdgcn_mfma_f32_16x16x32_bf16(a, b1, c1, 0, 0, 0);
        }
        __builtin_amdgcn_s_setprio(0);
        // write only this wave's e-slice [4*wid, 4*wid+4): C row=g4*4+r, col=m
        if (g4 == wid) {
            float4 bb = *(const float4*)&b2d[wid * 4];
            float bbv[4] = {bb.x, bb.y, bb.z, bb.w};
#pragma unroll
            for (int r = 0; r < 4; ++r) {
                ys[(4 * wid + r) * 32 + m]      = c0[r] + bbv[r];
                ys[(4 * wid + r) * 32 + 16 + m] = c1[r] + bbv[r];
            }
        }
    }
    asm volatile("s_waitcnt lgkmcnt(0)" ::: "memory");    // ys visible intra-wave
    __builtin_amdgcn_sched_barrier(0);

    // ---------------- phase 3: conv1d (asm dbuf Wt) + softmax ----------
    {
        float2 ac2[4];
#pragma unroll
        for (int j = 0; j < 4; ++j) ac2[j] = make_float2(0.f, 0.f);
        if (WBF) {
            WT_ISSUE8(bufB, wa);  wa += 4096;      // k = 2,3
            WAITV(8);                               // bufA ready (landed in p2)
            P3_PROC2(0, bufA);
            WT_ISSUE8(bufA, wa);  wa += 4096;      // k = 4,5
            WAITV(8);                               // bufB ready
            P3_PROC2(2, bufB);
            WT_ISSUE8(bufB, wa);                    // k = 6,7
            WAITV(8);                               // bufA (k=4,5) ready
            P3_PROC2(4, bufA);
            WAITV(0);                               // bufB (k=6,7) ready
            P3_PROC2(6, bufB);
        } else {
#pragma unroll
            for (int k = 0; k < 8; ++k) {
                const float2* yp = (const float2*)&ys[(g << 6) + (k << 3)];
                float2 y0 = yp[0], y1 = yp[1], y2 = yp[2], y3 = yp[3];
#pragma unroll
                for (int j = 0; j < 4; ++j) {
                    const float2* wr = (const float2*)(W1d + (((g << 7) + l + (j << 5)) << 6) + (k << 3));
                    ac2[j] += wr[0] * y0;
                    ac2[j] += wr[1] * y1;
                    ac2[j] += wr[2] * y2;
                    ac2[j] += wr[3] * y3;
                }
            }
        }
        float acc[4];
#pragma unroll
        for (int j = 0; j < 4; ++j)
            acc[j] = ac2[j].x + ac2[j].y + b1d[(g << 7) + (j << 5) + l];

        // softmax over v (= lane within 32-lane group), row u = 4g+j
#pragma unroll
        for (int j = 0; j < 4; ++j) {
            float mx = acc[j];
#pragma unroll
            for (int s = 16; s >= 1; s >>= 1) mx = fmaxf(mx, __shfl_xor(mx, s, 32));
            float p = __expf(acc[j] - mx);
            float ssum = p;
#pragma unroll
            for (int s = 16; s >= 1; s >>= 1) ssum += __shfl_xor(ssum, s, 32);
            float pv = __fdividef(p, ssum);
            zs16[((g << 2) + j) * 40 + l] = (u16t)pk_bf16(pv, pv);
        }
    }
    asm volatile("s_waitcnt lgkmcnt(0)" ::: "memory");
    __builtin_amdgcn_s_barrier();
    asm volatile("" ::: "memory");
    __builtin_amdgcn_sched_barrier(0);

    // ---------------- phase 4: out = attn . x via MFMA 32x32x16 ----------
    {
        // A frags: attn[u = l31][k = g2*8 + j (+16)]
        bf16x8 A0 = *(const bf16x8*)&zs16[l31 * 40 + g2 * 8];
        bf16x8 A1 = *(const bf16x8*)&zs16[l31 * 40 + 16 + g2 * 8];
        float* __restrict__ obase = out + (size_t)blk * 12288;
#pragma unroll
        for (int i = 0; i < 3; ++i) {
            const int d = wid * 96 + i * 32 + l31;
            const u16t* __restrict__ xc = xs16 + d;
            bf16x8 B0, B1;
#pragma unroll
            for (int j = 0; j < 8; ++j) {
                B0[j] = (short)xc[(g2 * 8 + j) * 392];
                B1[j] = (short)xc[(16 + g2 * 8 + j) * 392];
            }
            f32x16 acc16;
#pragma unroll
            for (int r = 0; r < 16; ++r) acc16[r] = 0.f;
            __builtin_amdgcn_s_setprio(1);
            acc16 = __builtin_amdgcn_mfma_f32_32x32x16_bf16(A0, B0, acc16, 0, 0, 0);
            acc16 = __builtin_amdgcn_mfma_f32_32x32x16_bf16(A1, B1, acc16, 0, 0, 0);
            __builtin_amdgcn_s_setprio(0);
            // NON-TEMPORAL stores: don't let the 201MB out-stream evict x
            // from L3 -- x stays Infinity-Cache-resident across replays.
#pragma unroll
            for (int r = 0; r < 16; ++r) {
                const int u = (r & 3) + 8 * (r >> 2) + 4 * g2;
                __builtin_nontemporal_store(acc16[r], &obase[u * 384 + d]);
            }
        }
    }
}

// ---------------------------------------------------------------------------
extern "C" void kernel_launch(void* const* d_in, const int* in_sizes, int n_in,
                              void* d_out, int out_size, void* d_ws, size_t ws_size,
                              hipStream_t stream) {
    const float* x   = (const float*)d_in[0];
    const float* W2d = (const float*)d_in[1];
    const float* b2d = (const float*)d_in[2];
    const float* W1d = (const float*)d_in[3];
    const float* b1d = (const float*)d_in[4];
    float* out = (float*)d_out;

    const size_t wt_bytes  = 8 * 8 * 128 * 8 * sizeof(u16t);   // 131072
    const size_t w2b_bytes = 16 * 384 * sizeof(u16t);          // 12288
    if (ws_size >= wt_bytes + w2b_bytes) {
        u16t* Wt = (u16t*)d_ws;
        u16t* W2b = (u16t*)((char*)d_ws + wt_bytes);
        prep_weights<<<35, 256, 0, stream>>>(W1d, W2d, Wt, (uint4*)W2b);
        dynamixer_fused<true><<<4096, 256, 0, stream>>>(x, W2d, b2d, W1d, b1d, Wt, W2b, out);
    } else {
        dynamixer_fused<false><<<4096, 256, 0, stream>>>(x, W2d, b2d, W1d, b1d, nullptr, nullptr, out);
    }
}